// Round 3
// baseline (432.253 us; speedup 1.0000x reference)
//
#include <hip/hip_runtime.h>

// KVGather, two-phase: precomputed inversion + lean store fan-out.
// out[b,p,t,:,:] = kv[b, r_idx[b,p,t], :, :]
// B=4, P2=64, TOPK=16, W2=49, C_KV=512
//
// Evidence so far (gather ~= dur_us - 262us harness fill):
//   R0 dest-major NT contiguous: 202us | R1 src-major NT interleaved: 173us
//   R2 src-major cached bursts:  166us | harness fill (plain stores): 6.27 TB/s
// => store mode and burst granularity both measured-null; write BW pinned
//    at ~2.5 TB/s. Remaining structural suspect: single-generation grid
//    (2048 blocks = exactly 8/CU, all lockstep: serial invert+load phase
//    idles the store pipe, Poisson(16) imbalance tail has no backfill),
//    plus 8x redundant r_idx inversion per region.
//
// Phase 1: invert r_idx once into ws (counts + dest lists, 129 KB).
// Phase 2: 4096 lean blocks (2 generations/CU), chunk = 392 float4
//          (= 49 full 128B lines), pure fan-out stores.

constexpr int B    = 4;
constexpr int P2   = 64;
constexpr int TOPK = 16;
constexpr int W2   = 49;
constexpr int C_KV = 512;
constexpr int REGION4 = W2 * C_KV / 4;      // 6272 float4 per region
constexpr int PT      = P2 * TOPK;          // 1024 dest slots per batch
constexpr int CAP     = 128;                // list capacity; Binom(1024,1/64) P(n>=128) ~ 1e-60
constexpr int CHUNKS  = 16;
constexpr int CHUNK4  = REGION4 / CHUNKS;   // 392 float4 = 6272 B = 49 lines
constexpr int TPB     = 256;
constexpr int TAIL    = CHUNK4 - TPB;       // 136 second-round threads

typedef float floatx4 __attribute__((ext_vector_type(4)));

// ws layout: int counts[B*P2]; int lists[B*P2][CAP]
__global__ __launch_bounds__(TPB) void invert_kernel(
    const int* __restrict__ r_idx,   // (B, P2, TOPK) flat, int32
    int* __restrict__ ws)
{
    const int b = blockIdx.x;
    const int t = threadIdx.x;
    __shared__ int s_cnt[P2];
    __shared__ int s_list[P2][CAP];          // 32 KB

    if (t < P2) s_cnt[t] = 0;
    __syncthreads();

    // 256 threads x 4 slots = 1024 dest slots of batch b
    const int4 rv = ((const int4*)(r_idx + b * PT))[t];
    const int vals[4] = { rv.x, rv.y, rv.z, rv.w };
    #pragma unroll
    for (int j = 0; j < 4; ++j) {
        const int src = vals[j];
        const int pos = atomicAdd(&s_cnt[src], 1);
        if (pos < CAP) s_list[src][pos] = b * PT + t * 4 + j;  // global dest slot
    }
    __syncthreads();

    int* cnt  = ws;
    int* list = ws + B * P2;
    if (t < P2) cnt[b * P2 + t] = min(s_cnt[t], CAP);
    for (int i = t; i < P2 * CAP; i += TPB)
        list[b * P2 * CAP + i] = ((const int*)s_list)[i];
}

__global__ __launch_bounds__(TPB) void fanout_kernel(
    const int* __restrict__ ws,
    const float* __restrict__ kv,    // (B, P2, W2, C_KV) flat
    float* __restrict__ out)         // (B, P2, TOPK, W2, C_KV) flat
{
    const int blk = blockIdx.x;
    const int c   = blk & (CHUNKS - 1);
    const int bs  = blk >> 4;                // b*P2 + src
    const int t   = threadIdx.x;

    const int* cnt  = ws;
    const int* list = ws + B * P2;

    __shared__ int s_list[CAP];
    const int n = cnt[bs];                   // uniform-address broadcast, L2-hot
    if (t < n) s_list[t] = list[bs * CAP + t];
    __syncthreads();

    // Stage this block's 6272 B chunk: 1 float4/thread + 136-thread tail.
    const floatx4* __restrict__ s4 =
        (const floatx4*)kv + (size_t)bs * REGION4 + c * CHUNK4;
    const floatx4 v0 = s4[t];
    floatx4 v1 = {};
    if (t < TAIL) v1 = s4[t + TPB];

    // Fan out: per dest, one 4 KB + one 2176 B full-line coalesced burst.
    floatx4* __restrict__ o4 = (floatx4*)out + c * CHUNK4;
    for (int k = 0; k < n; ++k) {
        floatx4* __restrict__ d = o4 + (size_t)s_list[k] * REGION4;
        d[t] = v0;
        if (t < TAIL) d[t + TPB] = v1;
    }
}

extern "C" void kernel_launch(void* const* d_in, const int* in_sizes, int n_in,
                              void* d_out, int out_size, void* d_ws, size_t ws_size,
                              hipStream_t stream) {
    const int*   r_idx = (const int*)d_in[0];
    const float* kv    = (const float*)d_in[1];
    float*       out   = (float*)d_out;
    int*         ws    = (int*)d_ws;         // needs 1 KB + 128 KB

    invert_kernel<<<B, TPB, 0, stream>>>(r_idx, ws);
    fanout_kernel<<<B * P2 * CHUNKS, TPB, 0, stream>>>(ws, kv, out);
}